// Round 6
// baseline (281.442 us; speedup 1.0000x reference)
//
#include <hip/hip_runtime.h>
#include <math.h>

#define NSAMP 32768   // 2^15 = 512 * 64
#define NDEL  512
#define NFR   16
#define BATCH 8
#define TWO_PI 6.283185307179586f

__device__ __forceinline__ float2 cmul(float2 a, float2 b) {
    return make_float2(a.x*b.x - a.y*b.y, a.x*b.y + a.y*b.x);
}
__device__ __forceinline__ float2 cadd(float2 a, float2 b){ return make_float2(a.x+b.x, a.y+b.y); }
__device__ __forceinline__ float2 csub(float2 a, float2 b){ return make_float2(a.x-b.x, a.y-b.y); }
// multiply by sign*i : fwd(sign=-1) -> -i*z = (y,-x) ; inv(+1) -> +i*z = (-y,x)
__device__ __forceinline__ float2 crot(float2 z, float sign){ return make_float2(-sign*z.y, sign*z.x); }

// LDS index swizzle to break power-of-2 strides (i -> i + i/8)
__device__ __forceinline__ int phi(int i){ return i + (i >> 3); }

__device__ __forceinline__ void bfly8(const float2 v[8], float sign, float2 X[8]) {
    const float S2 = 0.70710678118654752f;
    float2 t0 = cadd(v[0], v[4]), t1 = csub(v[0], v[4]);
    float2 t2 = cadd(v[2], v[6]), t3 = crot(csub(v[2], v[6]), sign);
    float2 E0 = cadd(t0, t2), E1 = cadd(t1, t3), E2 = csub(t0, t2), E3 = csub(t1, t3);
    float2 u0 = cadd(v[1], v[5]), u1 = csub(v[1], v[5]);
    float2 u2 = cadd(v[3], v[7]), u3 = crot(csub(v[3], v[7]), sign);
    float2 O0 = cadd(u0, u2), O1 = cadd(u1, u3), O2 = csub(u0, u2), O3 = csub(u1, u3);
    float2 c1 = make_float2( S2, sign*S2);
    float2 c3 = make_float2(-S2, sign*S2);
    float2 w1o = cmul(c1, O1);
    float2 w2o = crot(O2, sign);
    float2 w3o = cmul(c3, O3);
    X[0]=cadd(E0,O0);  X[4]=csub(E0,O0);
    X[1]=cadd(E1,w1o); X[5]=csub(E1,w1o);
    X[2]=cadd(E2,w2o); X[6]=csub(E2,w2o);
    X[3]=cadd(E3,w3o); X[7]=csub(E3,w3o);
}

__device__ __forceinline__ void twiddle_q(float2 v[8], float ang1) {
    float sa, ca; __sincosf(ang1, &sa, &ca);
    float2 w1 = make_float2(ca, sa), wq = w1;
#pragma unroll
    for (int q = 1; q < 8; ++q) { v[q] = cmul(v[q], wq); wq = cmul(wq, w1); }
}

// ---------------------------------------------------------------------------
// R11 = R10 (single persistent kernel, 4 phases, 3 device-scope barriers)
// with a HANG-PROOFED spin: bounded wait (~27 ms worst case) so a failed
// barrier produces a visibly wrong result instead of a queue hang (the
// r10 "container failed twice" is indistinguishable between infra flake
// and spin-hang; this removes the hang vector entirely).
//
// Evidence basis (r0/r2/r3, r9): each kernel dispatch carries ~8-10 µs of
// content-independent overhead (B+F=30.1 µs, M+O=22.4 µs vs ~1.5-5 µs
// modeled work each; not wg-count). All 512 one-wave blocks co-resident by
// capacity (2 blocks/CU: 9.2 KB LDS of 160 KB, 2 of 32 wave slots).
// __threadfence() = agent-scope fence -> cross-XCD L2 coherence for the
// transpose handoffs. Barrier counter MONOTONIC (no reset needed across
// bench iterations / graph replays / rocprof counter replays): target =
// round-up of fetch-add result to next multiple of 512.
__device__ unsigned g_bar = 0;

__device__ __forceinline__ void grid_barrier() {
    __syncthreads();                       // block arrival
    if (threadIdx.x == 0) {
        __threadfence();                   // release: agent-scope visibility
        unsigned old = __hip_atomic_fetch_add(&g_bar, 1u, __ATOMIC_ACQ_REL,
                                              __HIP_MEMORY_SCOPE_AGENT);
        unsigned tgt = (old & ~511u) + 512u;
        unsigned tries = 0;
        while (__hip_atomic_load(&g_bar, __ATOMIC_RELAXED,
                                 __HIP_MEMORY_SCOPE_AGENT) < tgt) {
            __builtin_amdgcn_s_sleep(1);
            if (++tries > 1000000u) break; // failsafe: wrong-output > hang
        }
        __threadfence();                   // acquire
    }
    __syncthreads();
}

__global__ void __launch_bounds__(64) mono_kernel(
        const float* __restrict__ impulse,
        const float* __restrict__ dsel,
        const float* __restrict__ damping,
        const float* __restrict__ filt,
        const float* __restrict__ noise,
        float2* __restrict__ A,            // At, later H
        float2* __restrict__ B,            // G spectrum rows
        float* __restrict__ out) {
    const int tid = threadIdx.x;           // 64 threads = 1 wave
    const int wid = blockIdx.x;            // 512 blocks, all co-resident

    __shared__ union {
        struct { float Wrow[NDEL]; float dl[512]; } bs;            // 4 KB
        struct { float2 buf[2][576]; } fs;                         // 9.2 KB
        struct { float2 Z[8][65]; float2 buf[576];
                 float fsig[NFR]; int cols[8]; } ms;               // 8.9 KB
    } u;

    // ======== phase 1: build (block = (b, f, quarter) window) ========
    {
        const int b   = wid >> 6;
        const int f   = (wid >> 2) & 15;
        const int sub = wid & 3;

        float v[8], m = -1e30f;
#pragma unroll
        for (int k = 0; k < 8; ++k) {
            v[k] = dsel[(b*NDEL + tid + 64*k)*NFR + f];
            m = fmaxf(m, v[k]);
        }
#pragma unroll
        for (int off = 1; off < 64; off <<= 1) m = fmaxf(m, __shfl_xor(m, off));
        float e[8], s = 0.0f;
#pragma unroll
        for (int k = 0; k < 8; ++k) { e[k] = __expf(v[k] - m); s += e[k]; }
#pragma unroll
        for (int off = 1; off < 64; off <<= 1) s += __shfl_xor(s, off);

        float damp = 1.0f/(1.0f + __expf(-damping[b])) * 0.9999f;
        float scale = damp / s;
#pragma unroll
        for (int k = 0; k < 8; ++k) u.bs.Wrow[tid + 64*k] = e[k] * scale;
        for (int k = tid; k < 512; k += 64) u.bs.dl[k] = 0.0f;
        __syncthreads();

        const unsigned start = ((unsigned)f << 11) + ((unsigned)sub << 9);
        const float fstart = (float)start;

        // small t (1..63): block-uniform t, lanes over multiples
        for (unsigned t = 1; t < 64; ++t) {
            float wt = u.bs.Wrow[t-1];
            unsigned q0 = (unsigned)(__fdividef(fstart, (float)t));
            unsigned n0 = q0 * t;
            while (n0 < start) n0 += t;
            while (n0 >= start + t) n0 -= t;
            for (unsigned i = (n0 - start) + (unsigned)tid * t; i < 512u; i += 64u * t)
                atomicAdd(&u.bs.dl[i], wt);
        }
        // large t (64..512): lane-parallel over t
        for (unsigned t = 64u + (unsigned)tid; t <= 512u; t += 64u) {
            float wt = u.bs.Wrow[t-1];
            unsigned q0 = (unsigned)(__fdividef(fstart, (float)t));
            unsigned n0 = q0 * t;
            while (n0 < start) n0 += t;
            while (n0 >= start + t) n0 -= t;
            for (unsigned i = n0 - start; i < 512u; i += t)
                atomicAdd(&u.bs.dl[i], wt);
        }
        __syncthreads();

        const int n1base = (int)(start >> 6);        // f*32 + sub*8
        float2* op = A + b*NSAMP + tid*512 + n1base;
#pragma unroll
        for (int q = 0; q < 8; ++q) {
            int n = (int)start + tid + 64*q;
            float pos = (n + 0.5f) * (1.0f/256.0f) - 0.5f;
            pos = fminf(fmaxf(pos, 0.0f), 127.0f);
            int i0 = (int)pos;
            float w2 = pos - (float)i0;
            int i1 = (i0 + 1 > 127) ? 127 : i0 + 1;
            float x0 = impulse[b*128 + i0]; x0 *= x0;
            float x1 = impulse[b*128 + i1]; x1 *= x1;
            float iv = (x0*(1.0f - w2) + x1*w2) * noise[b*NSAMP + n];
            op[q] = make_float2(u.bs.dl[tid + 64*q], iv);
        }
    }
    grid_barrier();

    // ======== phase 2: forward 512-pt FFT (block = (s, n2)) ========
    {
        const int j  = tid;
        const int s  = wid >> 6;
        const int n2 = wid & 63;
        const float sign = -1.0f;

        const float2* sp = A + s * NSAMP;
        float2 v[8], X[8];
#pragma unroll
        for (int q = 0; q < 8; ++q) v[q] = sp[n2*512 + j + 64*q];

        bfly8(v, sign, X);
#pragma unroll
        for (int r = 0; r < 8; ++r) u.fs.buf[0][phi(8*j + r)] = X[r];
        __syncthreads();
#pragma unroll
        for (int q = 0; q < 8; ++q) v[q] = u.fs.buf[0][phi(j + 64*q)];
        int jm = j & 7;
        twiddle_q(v, sign * TWO_PI * (float)jm * (1.0f/64.0f));
        bfly8(v, sign, X);
#pragma unroll
        for (int r = 0; r < 8; ++r) u.fs.buf[1][phi(((j>>3)<<6) + jm + (r<<3))] = X[r];
        __syncthreads();
#pragma unroll
        for (int q = 0; q < 8; ++q) v[q] = u.fs.buf[1][phi(j + 64*q)];
        twiddle_q(v, sign * TWO_PI * (float)j * (1.0f/512.0f));
        bfly8(v, sign, X);

        float2* dp = B + s * NSAMP + n2 * 512;
#pragma unroll
        for (int r = 0; r < 8; ++r) {
            int k1 = j + 64*r;
            int pr = (n2 * k1) & (NSAMP - 1);
            float sa, ca; __sincosf(sign * TWO_PI * (float)pr * (1.0f/32768.0f), &sa, &ca);
            dp[k1] = cmul(X[r], make_float2(ca, sa));
        }
    }
    grid_barrier();

    // ======== phase 3: mega (block = (s, g): 8 columns, 4 Hermitian pairs) ====
    {
        const int l  = tid;
        const int cc = l & 7, jj = l >> 3;
        const int s  = wid >> 6;
        const int g  = wid & 63;

        if (l < NFR) u.ms.fsig[l] = 1.0f/(1.0f + __expf(-filt[s*NFR + l]));
        if (l < 8) {
            int col;
            if (l < 4)        col = 4*g + l;
            else if (g == 0)  col = (l == 4) ? 256 : 512 - (l - 4);
            else              col = 512 - 4*g - (l - 4);
            u.ms.cols[l] = col;
        }
        __syncthreads();

        const float2* sp = B + s * NSAMP;
        const int mycol = u.ms.cols[cc];
        float2 v[8], X[8];

        // ---- step 1: forward 64-pt FFT (sign=-1) over n2, column mycol ----
#pragma unroll
        for (int q = 0; q < 8; ++q) v[q] = sp[(jj + 8*q)*512 + mycol];
        bfly8(v, -1.0f, X);
#pragma unroll
        for (int r = 0; r < 8; ++r) u.ms.buf[phi(cc*64 + jj*8 + r)] = X[r];
        __syncthreads();
#pragma unroll
        for (int q = 0; q < 8; ++q) v[q] = u.ms.buf[phi(cc*64 + jj + 8*q)];
        twiddle_q(v, -TWO_PI * (float)jj * (1.0f/64.0f));
        bfly8(v, -1.0f, X);
#pragma unroll
        for (int r = 0; r < 8; ++r) u.ms.Z[cc][jj + 8*r] = X[r];   // k2 = jj+8r
        __syncthreads();

        // ---- step 2: pointwise in LDS ----
        const float SCALE = 1.0f / (32768.0f * 181.01933598375618f); // N^{-3/2}
#pragma unroll
        for (int it = 0; it < 4; ++it) {
            int c  = l & 3;
            int k2 = (l >> 2) + 16*it;
            if (!(g == 0 && c == 0)) {
                int col = u.ms.cols[c];
                float2 Zk = u.ms.Z[c][k2];
                float2 Zr = u.ms.Z[c+4][63 - k2];
                float2 Zrc = make_float2(Zr.x, -Zr.y);
                float2 D = make_float2(0.5f*(Zk.x + Zrc.x), 0.5f*(Zk.y + Zrc.y));
                float2 df = make_float2(Zk.x - Zrc.x, Zk.y - Zrc.y);
                float2 I = make_float2(0.5f*df.y, -0.5f*df.x);
                int k = col + 512*k2;
                int jjb = (k <= NSAMP - k) ? k : NSAMP - k;
                float fv = 0.0f;
                if (jjb < NSAMP/2) {
                    float pos = (jjb + 0.5f) * (1.0f/1024.0f) - 0.5f;
                    pos = fminf(fmaxf(pos, 0.0f), 15.0f);
                    int i0 = (int)pos;
                    float w2 = pos - (float)i0;
                    int i1 = (i0 + 1 > 15) ? 15 : i0 + 1;
                    fv = u.ms.fsig[i0]*(1.0f - w2) + u.ms.fsig[i1]*w2;
                }
                float2 spec = cmul(D, I);
                float gs = fv * SCALE;
                u.ms.Z[c][k2]        = make_float2( spec.x*gs,  spec.y*gs);
                u.ms.Z[c+4][63 - k2] = make_float2( spec.x*gs, -spec.y*gs);
            }
        }
        if (g == 0) {
            if (l <= 32) {            // col 0: k2 <-> (64-k2)&63, k2 in [0,32]
                int k2 = l, k2p = (64 - k2) & 63;
                float2 Zk = u.ms.Z[0][k2];
                float2 Zr = u.ms.Z[0][k2p];
                float2 Zrc = make_float2(Zr.x, -Zr.y);
                float2 D = make_float2(0.5f*(Zk.x + Zrc.x), 0.5f*(Zk.y + Zrc.y));
                float2 df = make_float2(Zk.x - Zrc.x, Zk.y - Zrc.y);
                float2 I = make_float2(0.5f*df.y, -0.5f*df.x);
                int k = 512*k2;
                int jjb = (k <= NSAMP - k) ? k : NSAMP - k;
                float fv = 0.0f;
                if (jjb < NSAMP/2) {
                    float pos = (jjb + 0.5f) * (1.0f/1024.0f) - 0.5f;
                    pos = fminf(fmaxf(pos, 0.0f), 15.0f);
                    int i0 = (int)pos;
                    float w2 = pos - (float)i0;
                    int i1 = (i0 + 1 > 15) ? 15 : i0 + 1;
                    fv = u.ms.fsig[i0]*(1.0f - w2) + u.ms.fsig[i1]*w2;
                }
                float2 spec = cmul(D, I);
                float gs = fv * SCALE;
                u.ms.Z[0][k2]  = make_float2( spec.x*gs,  spec.y*gs);
                u.ms.Z[0][k2p] = make_float2( spec.x*gs, -spec.y*gs);
            }
            if (l < 32) {             // col 256: k2 <-> 63-k2, k2 in [0,32)
                int k2 = l, k2p = 63 - k2;
                float2 Zk = u.ms.Z[4][k2];
                float2 Zr = u.ms.Z[4][k2p];
                float2 Zrc = make_float2(Zr.x, -Zr.y);
                float2 D = make_float2(0.5f*(Zk.x + Zrc.x), 0.5f*(Zk.y + Zrc.y));
                float2 df = make_float2(Zk.x - Zrc.x, Zk.y - Zrc.y);
                float2 I = make_float2(0.5f*df.y, -0.5f*df.x);
                int k = 256 + 512*k2;
                int jjb = (k <= NSAMP - k) ? k : NSAMP - k;
                float fv = 0.0f;
                {
                    float pos = (jjb + 0.5f) * (1.0f/1024.0f) - 0.5f;
                    pos = fminf(fmaxf(pos, 0.0f), 15.0f);
                    int i0 = (int)pos;
                    float w2 = pos - (float)i0;
                    int i1 = (i0 + 1 > 15) ? 15 : i0 + 1;
                    fv = u.ms.fsig[i0]*(1.0f - w2) + u.ms.fsig[i1]*w2;
                }
                float2 spec = cmul(D, I);
                float gs = fv * SCALE;
                u.ms.Z[4][k2]  = make_float2( spec.x*gs,  spec.y*gs);
                u.ms.Z[4][k2p] = make_float2( spec.x*gs, -spec.y*gs);
            }
        }
        __syncthreads();

        // ---- step 3: inverse 64-pt FFT (sign=+1) over k2, column mycol ----
#pragma unroll
        for (int q = 0; q < 8; ++q) v[q] = u.ms.Z[cc][jj + 8*q];
        bfly8(v, 1.0f, X);
#pragma unroll
        for (int r = 0; r < 8; ++r) u.ms.buf[phi(cc*64 + jj*8 + r)] = X[r];
        __syncthreads();
#pragma unroll
        for (int q = 0; q < 8; ++q) v[q] = u.ms.buf[phi(cc*64 + jj + 8*q)];
        twiddle_q(v, TWO_PI * (float)jj * (1.0f/64.0f));
        bfly8(v, 1.0f, X);

        float2* hp = A + s * NSAMP + mycol;
#pragma unroll
        for (int r = 0; r < 8; ++r) {
            int n2 = jj + 8*r;
            int pr = (n2 * mycol) & (NSAMP - 1);
            float sa, ca; __sincosf(TWO_PI * (float)pr * (1.0f/32768.0f), &sa, &ca);
            hp[n2*512] = cmul(X[r], make_float2(ca, sa));
        }
    }
    grid_barrier();

    // ======== phase 4: inverse 512-pt FFT + real output (block = (s, n2)) ====
    {
        const int j  = tid;
        const int s  = wid >> 6;
        const int n2 = wid & 63;
        const float sign = 1.0f;

        const float2* sp = A + s * NSAMP;
        float2 v[8], X[8];
#pragma unroll
        for (int q = 0; q < 8; ++q) v[q] = sp[n2*512 + j + 64*q];

        bfly8(v, sign, X);
#pragma unroll
        for (int r = 0; r < 8; ++r) u.fs.buf[0][phi(8*j + r)] = X[r];
        __syncthreads();
#pragma unroll
        for (int q = 0; q < 8; ++q) v[q] = u.fs.buf[0][phi(j + 64*q)];
        int jm = j & 7;
        twiddle_q(v, sign * TWO_PI * (float)jm * (1.0f/64.0f));
        bfly8(v, sign, X);
#pragma unroll
        for (int r = 0; r < 8; ++r) u.fs.buf[1][phi(((j>>3)<<6) + jm + (r<<3))] = X[r];
        __syncthreads();
#pragma unroll
        for (int q = 0; q < 8; ++q) v[q] = u.fs.buf[1][phi(j + 64*q)];
        twiddle_q(v, sign * TWO_PI * (float)j * (1.0f/512.0f));
        bfly8(v, sign, X);

        float* op = out + s * NSAMP + n2;
#pragma unroll
        for (int r = 0; r < 8; ++r) op[64*j + 4096*r] = X[r].x;
    }
}

// ---------------------------------------------------------------------------
extern "C" void kernel_launch(void* const* d_in, const int* in_sizes, int n_in,
                              void* d_out, int out_size, void* d_ws, size_t ws_size,
                              hipStream_t stream) {
    const float* impulse = (const float*)d_in[0];   // [8,128]
    const float* dsel    = (const float*)d_in[1];   // [8,512,16]
    const float* damping = (const float*)d_in[2];   // [8,1]
    const float* filt    = (const float*)d_in[3];   // [8,16]
    const float* noise   = (const float*)d_in[4];   // [8,1,32768]
    // d_in[5] (delays, 64 MB): pure structure delays[i,n] = [ (i+1) | n ] — never read.
    float* out = (float*)d_out;                     // [8,32768]

    float2* A = (float2*)d_ws;                      // 2 MB
    float2* B = A + BATCH * NSAMP;                  // 2 MB

    // Cost model (r0-r4): dur = fills (~82 us, harness) + kernels. Four
    // separate kernels carried ~8-10 us each of content-independent
    // dispatch/flush overhead (B+F=30.1, M+O=22.4 measured vs ~1.5-5 us
    // modeled work; wg-count ruled out in r9). R11 = R10 persistent-kernel
    // experiment with a bounded (hang-proof) barrier spin.
    mono_kernel<<<dim3(512), dim3(64), 0, stream>>>(impulse, dsel, damping,
                                                    filt, noise, A, B, out);
}

// Round 7
// 213.023 us; speedup vs baseline: 1.3212x; 1.3212x over previous
//
#include <hip/hip_runtime.h>
#include <math.h>

#define NSAMP 32768   // 2^15 = 512 * 64
#define NDEL  512
#define NFR   16
#define BATCH 8
#define TWO_PI 6.283185307179586f

__device__ __forceinline__ float2 cmul(float2 a, float2 b) {
    return make_float2(a.x*b.x - a.y*b.y, a.x*b.y + a.y*b.x);
}
__device__ __forceinline__ float2 cadd(float2 a, float2 b){ return make_float2(a.x+b.x, a.y+b.y); }
__device__ __forceinline__ float2 csub(float2 a, float2 b){ return make_float2(a.x-b.x, a.y-b.y); }
// multiply by sign*i : fwd(sign=-1) -> -i*z = (y,-x) ; inv(+1) -> +i*z = (-y,x)
__device__ __forceinline__ float2 crot(float2 z, float sign){ return make_float2(-sign*z.y, sign*z.x); }

// LDS index swizzle to break power-of-2 strides (i -> i + i/8)
__device__ __forceinline__ int phi(int i){ return i + (i >> 3); }

__device__ __forceinline__ void bfly8(const float2 v[8], float sign, float2 X[8]) {
    const float S2 = 0.70710678118654752f;
    float2 t0 = cadd(v[0], v[4]), t1 = csub(v[0], v[4]);
    float2 t2 = cadd(v[2], v[6]), t3 = crot(csub(v[2], v[6]), sign);
    float2 E0 = cadd(t0, t2), E1 = cadd(t1, t3), E2 = csub(t0, t2), E3 = csub(t1, t3);
    float2 u0 = cadd(v[1], v[5]), u1 = csub(v[1], v[5]);
    float2 u2 = cadd(v[3], v[7]), u3 = crot(csub(v[3], v[7]), sign);
    float2 O0 = cadd(u0, u2), O1 = cadd(u1, u3), O2 = csub(u0, u2), O3 = csub(u1, u3);
    float2 c1 = make_float2( S2, sign*S2);
    float2 c3 = make_float2(-S2, sign*S2);
    float2 w1o = cmul(c1, O1);
    float2 w2o = crot(O2, sign);
    float2 w3o = cmul(c3, O3);
    X[0]=cadd(E0,O0);  X[4]=csub(E0,O0);
    X[1]=cadd(E1,w1o); X[5]=csub(E1,w1o);
    X[2]=cadd(E2,w2o); X[6]=csub(E2,w2o);
    X[3]=cadd(E3,w3o); X[7]=csub(E3,w3o);
}

__device__ __forceinline__ void twiddle_q(float2 v[8], float ang1) {
    float sa, ca; __sincosf(ang1, &sa, &ca);
    float2 w1 = make_float2(ca, sa), wq = w1;
#pragma unroll
    for (int q = 1; q < 8; ++q) { v[q] = cmul(v[q], wq); wq = cmul(wq, w1); }
}

// mega column mapping: group g, slot idx in [0,8)
__device__ __forceinline__ int colof(int idx, int g) {
    if (idx < 4) return 4*g + idx;
    if (g == 0)  return (idx == 4) ? 256 : 512 - (idx - 4);
    return 512 - 4*g - (idx - 4);
}

// ---------------------------------------------------------------------------
// Sync-cost hierarchy, MEASURED on this part (r0-r11):
//   intra-block __syncthreads ~0.04 us  <<  kernel boundary ~10 us
//   <<  in-kernel device-wide barrier ~62 us (r11: mono=203 us = ~15 work
//       + 3 x 62; reproduces r5's grid.sync ~75 us).
// => minimize KERNEL NODES, never use device barriers, do all transposes
//    with intra-block sync. The 3 transposes are per-batch (256 KB each),
//    so one 1024-thread block per batch runs fwdFFT+mega+iFFT internally.
// ---------------------------------------------------------------------------
// Kernel 1: fused softmax + damping + divisor-sieve + impulse/noise build.
// One wave-block per (b, f, quarter): 512-sample window (r3-verified).
__global__ void build_kernel(const float* __restrict__ impulse,
                             const float* __restrict__ dsel,
                             const float* __restrict__ damping,
                             const float* __restrict__ noise,
                             float2* __restrict__ At) {
    const int b   = blockIdx.x >> 6;
    const int f   = (blockIdx.x >> 2) & 15;
    const int sub = blockIdx.x & 3;
    const int tid = threadIdx.x;                 // 64 threads = 1 wave
    __shared__ float Wrow[NDEL];
    __shared__ float dl[512];

    float v[8], m = -1e30f;
#pragma unroll
    for (int k = 0; k < 8; ++k) {
        v[k] = dsel[(b*NDEL + tid + 64*k)*NFR + f];
        m = fmaxf(m, v[k]);
    }
#pragma unroll
    for (int off = 1; off < 64; off <<= 1) m = fmaxf(m, __shfl_xor(m, off));
    float e[8], s = 0.0f;
#pragma unroll
    for (int k = 0; k < 8; ++k) { e[k] = __expf(v[k] - m); s += e[k]; }
#pragma unroll
    for (int off = 1; off < 64; off <<= 1) s += __shfl_xor(s, off);

    float damp = 1.0f/(1.0f + __expf(-damping[b])) * 0.9999f;
    float scale = damp / s;
#pragma unroll
    for (int k = 0; k < 8; ++k) Wrow[tid + 64*k] = e[k] * scale;
    for (int k = tid; k < 512; k += 64) dl[k] = 0.0f;
    __syncthreads();

    const unsigned start = ((unsigned)f << 11) + ((unsigned)sub << 9);
    const float fstart = (float)start;

    // small t (1..63): block-uniform t, lanes over multiples
    for (unsigned t = 1; t < 64; ++t) {
        float wt = Wrow[t-1];
        unsigned q0 = (unsigned)(__fdividef(fstart, (float)t));
        unsigned n0 = q0 * t;
        while (n0 < start) n0 += t;
        while (n0 >= start + t) n0 -= t;
        for (unsigned i = (n0 - start) + (unsigned)tid * t; i < 512u; i += 64u * t)
            atomicAdd(&dl[i], wt);
    }
    // large t (64..512): lane-parallel over t
    for (unsigned t = 64u + (unsigned)tid; t <= 512u; t += 64u) {
        float wt = Wrow[t-1];
        unsigned q0 = (unsigned)(__fdividef(fstart, (float)t));
        unsigned n0 = q0 * t;
        while (n0 < start) n0 += t;
        while (n0 >= start + t) n0 -= t;
        for (unsigned i = n0 - start; i < 512u; i += t)
            atomicAdd(&dl[i], wt);
    }
    __syncthreads();

    const int n1base = (int)(start >> 6);        // f*32 + sub*8
    float2* op = At + b*NSAMP + tid*512 + n1base;
#pragma unroll
    for (int q = 0; q < 8; ++q) {
        int n = (int)start + tid + 64*q;
        float pos = (n + 0.5f) * (1.0f/256.0f) - 0.5f;
        pos = fminf(fmaxf(pos, 0.0f), 127.0f);
        int i0 = (int)pos;
        float w2 = pos - (float)i0;
        int i1 = (i0 + 1 > 127) ? 127 : i0 + 1;
        float x0 = impulse[b*128 + i0]; x0 *= x0;
        float x1 = impulse[b*128 + i1]; x1 *= x1;
        float iv = (x0*(1.0f - w2) + x1*w2) * noise[b*NSAMP + n];
        op[q] = make_float2(dl[tid + 64*q], iv);
    }
}

// ---------------------------------------------------------------------------
// Kernel 2: entire post-build pipeline for ONE BATCH per 1024-thread block.
//   phase A: 64 fwd 512-pt FFTs over n1 (4 per wave, private LDS slice)
//            + four-step twiddle -> G (global, B buffer)
//   phase B: mega per column-group g (4 per wave): 64-pt FFT over n2,
//            Hermitian split D*I*fv*SCALE, inverse 64-pt FFT, twiddle -> H (A)
//   phase C: 64 inv 512-pt FFTs over k1 (4 per wave) -> real out
// Cross-wave handoffs (the transposes) go through global G/H but stay on
// this block's CU/XCD; __threadfence() (buffer_inv) between phases kills
// stale-L1 lines from prior graph replays; __syncthreads orders waves.
__global__ void __launch_bounds__(1024) fft_conv_kernel(
        float2* __restrict__ A,            // in: At (build output); then H
        float2* __restrict__ B,            // scratch: G
        const float* __restrict__ filt,
        float* __restrict__ out) {
    const int w = threadIdx.x >> 6;        // wave 0..15
    const int l = threadIdx.x & 63;        // lane
    const int s = blockIdx.x;              // batch

    __shared__ float2 SL[16][1152];        // 147456 B: 9216 B per-wave slice
    __shared__ float fsig[NFR];

    if (threadIdx.x < NFR)
        fsig[threadIdx.x] = 1.0f/(1.0f + __expf(-filt[s*NFR + threadIdx.x]));
    __syncthreads();

    // ======== phase A: forward 512-pt FFT over n1, n2 = it*16 + w ========
    {
        float2* buf0 = &SL[w][0];
        float2* buf1 = &SL[w][576];
        const float sign = -1.0f;
        const float2* sp = A + s * NSAMP;
        float2* gp = B + s * NSAMP;
        for (int it = 0; it < 4; ++it) {
            const int n2 = it * 16 + w;
            float2 v[8], X[8];
#pragma unroll
            for (int q = 0; q < 8; ++q) v[q] = sp[n2*512 + l + 64*q];
            bfly8(v, sign, X);
#pragma unroll
            for (int r = 0; r < 8; ++r) buf0[phi(8*l + r)] = X[r];
            __syncthreads();
#pragma unroll
            for (int q = 0; q < 8; ++q) v[q] = buf0[phi(l + 64*q)];
            int jm = l & 7;
            twiddle_q(v, sign * TWO_PI * (float)jm * (1.0f/64.0f));
            bfly8(v, sign, X);
#pragma unroll
            for (int r = 0; r < 8; ++r) buf1[phi(((l>>3)<<6) + jm + (r<<3))] = X[r];
            __syncthreads();
#pragma unroll
            for (int q = 0; q < 8; ++q) v[q] = buf1[phi(l + 64*q)];
            twiddle_q(v, sign * TWO_PI * (float)l * (1.0f/512.0f));
            bfly8(v, sign, X);

            float2* dp = gp + n2 * 512;
#pragma unroll
            for (int r = 0; r < 8; ++r) {
                int k1 = l + 64*r;
                int pr = (n2 * k1) & (NSAMP - 1);
                float sa, ca; __sincosf(sign * TWO_PI * (float)pr * (1.0f/32768.0f), &sa, &ca);
                dp[k1] = cmul(X[r], make_float2(ca, sa));
            }
        }
    }
    __threadfence();          // drain stores to L2 + invalidate L1 (replay-stale)
    __syncthreads();

    // ======== phase B: mega per column-group, g = it*16 + w ========
    {
        float2 (*Z)[65] = reinterpret_cast<float2(*)[65]>(&SL[w][0]);   // 520 f2
        float2* mbuf = &SL[w][520];                                     // 576 f2
        const int cc = l & 7, jj = l >> 3;
        const float2* sp = B + s * NSAMP;
        const float SCALE = 1.0f / (32768.0f * 181.01933598375618f);    // N^{-3/2}

        for (int it = 0; it < 4; ++it) {
            const int g = it * 16 + w;
            const int mycol = colof(cc, g);
            float2 v[8], X[8];

            // ---- step 1: forward 64-pt FFT (sign=-1) over n2 ----
#pragma unroll
            for (int q = 0; q < 8; ++q) v[q] = sp[(jj + 8*q)*512 + mycol];
            bfly8(v, -1.0f, X);
#pragma unroll
            for (int r = 0; r < 8; ++r) mbuf[phi(cc*64 + jj*8 + r)] = X[r];
            __syncthreads();
#pragma unroll
            for (int q = 0; q < 8; ++q) v[q] = mbuf[phi(cc*64 + jj + 8*q)];
            twiddle_q(v, -TWO_PI * (float)jj * (1.0f/64.0f));
            bfly8(v, -1.0f, X);
#pragma unroll
            for (int r = 0; r < 8; ++r) Z[cc][jj + 8*r] = X[r];   // k2 = jj+8r
            __syncthreads();

            // ---- step 2: pointwise in LDS ----
#pragma unroll
            for (int itp = 0; itp < 4; ++itp) {
                int c  = l & 3;
                int k2 = (l >> 2) + 16*itp;
                if (!(g == 0 && c == 0)) {
                    int col = colof(c, g);
                    float2 Zk = Z[c][k2];
                    float2 Zr = Z[c+4][63 - k2];
                    float2 Zrc = make_float2(Zr.x, -Zr.y);
                    float2 D = make_float2(0.5f*(Zk.x + Zrc.x), 0.5f*(Zk.y + Zrc.y));
                    float2 df = make_float2(Zk.x - Zrc.x, Zk.y - Zrc.y);
                    float2 I = make_float2(0.5f*df.y, -0.5f*df.x);
                    int k = col + 512*k2;
                    int jjb = (k <= NSAMP - k) ? k : NSAMP - k;
                    float fv = 0.0f;
                    if (jjb < NSAMP/2) {
                        float pos = (jjb + 0.5f) * (1.0f/1024.0f) - 0.5f;
                        pos = fminf(fmaxf(pos, 0.0f), 15.0f);
                        int i0 = (int)pos;
                        float w2 = pos - (float)i0;
                        int i1 = (i0 + 1 > 15) ? 15 : i0 + 1;
                        fv = fsig[i0]*(1.0f - w2) + fsig[i1]*w2;
                    }
                    float2 spec = cmul(D, I);
                    float gs = fv * SCALE;
                    Z[c][k2]        = make_float2( spec.x*gs,  spec.y*gs);
                    Z[c+4][63 - k2] = make_float2( spec.x*gs, -spec.y*gs);
                }
            }
            if (g == 0) {
                if (l <= 32) {            // col 0: k2 <-> (64-k2)&63
                    int k2 = l, k2p = (64 - k2) & 63;
                    float2 Zk = Z[0][k2];
                    float2 Zr = Z[0][k2p];
                    float2 Zrc = make_float2(Zr.x, -Zr.y);
                    float2 D = make_float2(0.5f*(Zk.x + Zrc.x), 0.5f*(Zk.y + Zrc.y));
                    float2 df = make_float2(Zk.x - Zrc.x, Zk.y - Zrc.y);
                    float2 I = make_float2(0.5f*df.y, -0.5f*df.x);
                    int k = 512*k2;
                    int jjb = (k <= NSAMP - k) ? k : NSAMP - k;
                    float fv = 0.0f;
                    if (jjb < NSAMP/2) {
                        float pos = (jjb + 0.5f) * (1.0f/1024.0f) - 0.5f;
                        pos = fminf(fmaxf(pos, 0.0f), 15.0f);
                        int i0 = (int)pos;
                        float w2 = pos - (float)i0;
                        int i1 = (i0 + 1 > 15) ? 15 : i0 + 1;
                        fv = fsig[i0]*(1.0f - w2) + fsig[i1]*w2;
                    }
                    float2 spec = cmul(D, I);
                    float gs = fv * SCALE;
                    Z[0][k2]  = make_float2( spec.x*gs,  spec.y*gs);
                    Z[0][k2p] = make_float2( spec.x*gs, -spec.y*gs);
                }
                if (l < 32) {             // col 256: k2 <-> 63-k2
                    int k2 = l, k2p = 63 - k2;
                    float2 Zk = Z[4][k2];
                    float2 Zr = Z[4][k2p];
                    float2 Zrc = make_float2(Zr.x, -Zr.y);
                    float2 D = make_float2(0.5f*(Zk.x + Zrc.x), 0.5f*(Zk.y + Zrc.y));
                    float2 df = make_float2(Zk.x - Zrc.x, Zk.y - Zrc.y);
                    float2 I = make_float2(0.5f*df.y, -0.5f*df.x);
                    int k = 256 + 512*k2;
                    int jjb = (k <= NSAMP - k) ? k : NSAMP - k;
                    float fv;
                    {
                        float pos = (jjb + 0.5f) * (1.0f/1024.0f) - 0.5f;
                        pos = fminf(fmaxf(pos, 0.0f), 15.0f);
                        int i0 = (int)pos;
                        float w2 = pos - (float)i0;
                        int i1 = (i0 + 1 > 15) ? 15 : i0 + 1;
                        fv = fsig[i0]*(1.0f - w2) + fsig[i1]*w2;
                    }
                    float2 spec = cmul(D, I);
                    float gs = fv * SCALE;
                    Z[4][k2]  = make_float2( spec.x*gs,  spec.y*gs);
                    Z[4][k2p] = make_float2( spec.x*gs, -spec.y*gs);
                }
            }
            __syncthreads();

            // ---- step 3: inverse 64-pt FFT (sign=+1) over k2 ----
#pragma unroll
            for (int q = 0; q < 8; ++q) v[q] = Z[cc][jj + 8*q];
            bfly8(v, 1.0f, X);
#pragma unroll
            for (int r = 0; r < 8; ++r) mbuf[phi(cc*64 + jj*8 + r)] = X[r];
            __syncthreads();
#pragma unroll
            for (int q = 0; q < 8; ++q) v[q] = mbuf[phi(cc*64 + jj + 8*q)];
            twiddle_q(v, TWO_PI * (float)jj * (1.0f/64.0f));
            bfly8(v, 1.0f, X);

            float2* hp = A + s * NSAMP + mycol;
#pragma unroll
            for (int r = 0; r < 8; ++r) {
                int n2 = jj + 8*r;
                int pr = (n2 * mycol) & (NSAMP - 1);
                float sa, ca; __sincosf(TWO_PI * (float)pr * (1.0f/32768.0f), &sa, &ca);
                hp[n2*512] = cmul(X[r], make_float2(ca, sa));
            }
        }
    }
    __threadfence();
    __syncthreads();

    // ======== phase C: inverse 512-pt FFT over k1 + real out ========
    {
        float2* buf0 = &SL[w][0];
        float2* buf1 = &SL[w][576];
        const float sign = 1.0f;
        const float2* sp = A + s * NSAMP;
        for (int it = 0; it < 4; ++it) {
            const int n2 = it * 16 + w;
            float2 v[8], X[8];
#pragma unroll
            for (int q = 0; q < 8; ++q) v[q] = sp[n2*512 + l + 64*q];
            bfly8(v, sign, X);
#pragma unroll
            for (int r = 0; r < 8; ++r) buf0[phi(8*l + r)] = X[r];
            __syncthreads();
#pragma unroll
            for (int q = 0; q < 8; ++q) v[q] = buf0[phi(l + 64*q)];
            int jm = l & 7;
            twiddle_q(v, sign * TWO_PI * (float)jm * (1.0f/64.0f));
            bfly8(v, sign, X);
#pragma unroll
            for (int r = 0; r < 8; ++r) buf1[phi(((l>>3)<<6) + jm + (r<<3))] = X[r];
            __syncthreads();
#pragma unroll
            for (int q = 0; q < 8; ++q) v[q] = buf1[phi(l + 64*q)];
            twiddle_q(v, sign * TWO_PI * (float)l * (1.0f/512.0f));
            bfly8(v, sign, X);

            float* op = out + s * NSAMP + n2;
#pragma unroll
            for (int r = 0; r < 8; ++r) op[64*l + 4096*r] = X[r].x;
        }
    }
}

// ---------------------------------------------------------------------------
extern "C" void kernel_launch(void* const* d_in, const int* in_sizes, int n_in,
                              void* d_out, int out_size, void* d_ws, size_t ws_size,
                              hipStream_t stream) {
    const float* impulse = (const float*)d_in[0];   // [8,128]
    const float* dsel    = (const float*)d_in[1];   // [8,512,16]
    const float* damping = (const float*)d_in[2];   // [8,1]
    const float* filt    = (const float*)d_in[3];   // [8,16]
    const float* noise   = (const float*)d_in[4];   // [8,1,32768]
    // d_in[5] (delays, 64 MB): pure structure delays[i,n] = [ (i+1) | n ] — never read.
    float* out = (float*)d_out;                     // [8,32768]

    float2* A = (float2*)d_ws;                      // 2 MB (At, then H)
    float2* B = A + BATCH * NSAMP;                  // 2 MB (G)

    // Measured sync hierarchy (r0-r11): __syncthreads ~0.04 us, kernel
    // boundary ~10 us, in-kernel device barrier ~62 us. R12: collapse the
    // three per-batch transposes into one 1024-thread block per batch
    // (intra-block sync only) -> 4 kernel nodes become 2.
    build_kernel   <<<dim3(512), dim3(64),   0, stream>>>(impulse, dsel, damping, noise, A);
    fft_conv_kernel<<<dim3(BATCH), dim3(1024), 0, stream>>>(A, B, filt, out);
}

// Round 8
// 135.545 us; speedup vs baseline: 2.0764x; 1.5716x over previous
//
#include <hip/hip_runtime.h>
#include <math.h>

#define NSAMP 32768   // 2^15 = 512 * 64
#define NDEL  512
#define NFR   16
#define BATCH 8
#define TWO_PI 6.283185307179586f

__device__ __forceinline__ float2 cmul(float2 a, float2 b) {
    return make_float2(a.x*b.x - a.y*b.y, a.x*b.y + a.y*b.x);
}
__device__ __forceinline__ float2 cadd(float2 a, float2 b){ return make_float2(a.x+b.x, a.y+b.y); }
__device__ __forceinline__ float2 csub(float2 a, float2 b){ return make_float2(a.x-b.x, a.y-b.y); }
// multiply by sign*i : fwd(sign=-1) -> -i*z = (y,-x) ; inv(+1) -> +i*z = (-y,x)
__device__ __forceinline__ float2 crot(float2 z, float sign){ return make_float2(-sign*z.y, sign*z.x); }

// LDS index swizzle to break power-of-2 strides (i -> i + i/8)
__device__ __forceinline__ int phi(int i){ return i + (i >> 3); }

__device__ __forceinline__ void bfly8(const float2 v[8], float sign, float2 X[8]) {
    const float S2 = 0.70710678118654752f;
    float2 t0 = cadd(v[0], v[4]), t1 = csub(v[0], v[4]);
    float2 t2 = cadd(v[2], v[6]), t3 = crot(csub(v[2], v[6]), sign);
    float2 E0 = cadd(t0, t2), E1 = cadd(t1, t3), E2 = csub(t0, t2), E3 = csub(t1, t3);
    float2 u0 = cadd(v[1], v[5]), u1 = csub(v[1], v[5]);
    float2 u2 = cadd(v[3], v[7]), u3 = crot(csub(v[3], v[7]), sign);
    float2 O0 = cadd(u0, u2), O1 = cadd(u1, u3), O2 = csub(u0, u2), O3 = csub(u1, u3);
    float2 c1 = make_float2( S2, sign*S2);
    float2 c3 = make_float2(-S2, sign*S2);
    float2 w1o = cmul(c1, O1);
    float2 w2o = crot(O2, sign);
    float2 w3o = cmul(c3, O3);
    X[0]=cadd(E0,O0);  X[4]=csub(E0,O0);
    X[1]=cadd(E1,w1o); X[5]=csub(E1,w1o);
    X[2]=cadd(E2,w2o); X[6]=csub(E2,w2o);
    X[3]=cadd(E3,w3o); X[7]=csub(E3,w3o);
}

__device__ __forceinline__ void twiddle_q(float2 v[8], float ang1) {
    float sa, ca; __sincosf(ang1, &sa, &ca);
    float2 w1 = make_float2(ca, sa), wq = w1;
#pragma unroll
    for (int q = 1; q < 8; ++q) { v[q] = cmul(v[q], wq); wq = cmul(wq, w1); }
}

// ---------------------------------------------------------------------------
// FINAL STRUCTURE (r0-r12 ledger):
//   4-kernel windowed  = 134.5/135.2 us   <- best (this file)
//   3-kernel column-fused = 171 (+37: per-mark W reads, divergent sieve)
//   4-kernel 4-wave blocks = 138 (+3: wg-count is not the cost)
//   1-kernel persistent    = 281 (+146: device barrier ~62 us each)
//   2-kernel per-batch fat = 213 (+78: 8 blocks -> no latency hiding)
// Proof sketch: windowed build (required by sieve, r2) pins the contiguous
// index to n; every Cooley-Tukey split of 32768 then needs the strided
// 512-pt stage AFTER a global transpose -> 4 stream-ordered phases is
// minimal. Budget: ~82 us harness ws-poison fills + 4 x ~10 us node
// overhead + ~12 us work ~= 134 us measured floor.
// ---------------------------------------------------------------------------
// Kernel 1: fused softmax + damping + divisor-sieve + impulse/noise build.
// One wave-block per (b, f, quarter): 512-sample window. Output TRANSPOSED:
// A_T[b][n2][n1] with n = 64*n1 + n2 (thread t = n2 writes 8 consecutive).
__global__ void build_kernel(const float* __restrict__ impulse,
                             const float* __restrict__ dsel,
                             const float* __restrict__ damping,
                             const float* __restrict__ noise,
                             float2* __restrict__ At) {
    const int b   = blockIdx.x >> 6;
    const int f   = (blockIdx.x >> 2) & 15;
    const int sub = blockIdx.x & 3;
    const int tid = threadIdx.x;                 // 64 threads = 1 wave
    __shared__ float Wrow[NDEL];
    __shared__ float dl[512];

    float v[8], m = -1e30f;
#pragma unroll
    for (int k = 0; k < 8; ++k) {
        v[k] = dsel[(b*NDEL + tid + 64*k)*NFR + f];
        m = fmaxf(m, v[k]);
    }
#pragma unroll
    for (int off = 1; off < 64; off <<= 1) m = fmaxf(m, __shfl_xor(m, off));
    float e[8], s = 0.0f;
#pragma unroll
    for (int k = 0; k < 8; ++k) { e[k] = __expf(v[k] - m); s += e[k]; }
#pragma unroll
    for (int off = 1; off < 64; off <<= 1) s += __shfl_xor(s, off);

    float damp = 1.0f/(1.0f + __expf(-damping[b])) * 0.9999f;
    float scale = damp / s;
#pragma unroll
    for (int k = 0; k < 8; ++k) Wrow[tid + 64*k] = e[k] * scale;
    for (int k = tid; k < 512; k += 64) dl[k] = 0.0f;
    __syncthreads();

    const unsigned start = ((unsigned)f << 11) + ((unsigned)sub << 9);
    const float fstart = (float)start;

    // small t (1..63): block-uniform t, lanes over multiples
    for (unsigned t = 1; t < 64; ++t) {
        float wt = Wrow[t-1];
        unsigned q0 = (unsigned)(__fdividef(fstart, (float)t));
        unsigned n0 = q0 * t;
        while (n0 < start) n0 += t;
        while (n0 >= start + t) n0 -= t;
        for (unsigned i = (n0 - start) + (unsigned)tid * t; i < 512u; i += 64u * t)
            atomicAdd(&dl[i], wt);
    }
    // large t (64..512): lane-parallel over t
    for (unsigned t = 64u + (unsigned)tid; t <= 512u; t += 64u) {
        float wt = Wrow[t-1];
        unsigned q0 = (unsigned)(__fdividef(fstart, (float)t));
        unsigned n0 = q0 * t;
        while (n0 < start) n0 += t;
        while (n0 >= start + t) n0 -= t;
        for (unsigned i = n0 - start; i < 512u; i += t)
            atomicAdd(&dl[i], wt);
    }
    __syncthreads();

    const int n1base = (int)(start >> 6);        // f*32 + sub*8
    float2* op = At + b*NSAMP + tid*512 + n1base;
#pragma unroll
    for (int q = 0; q < 8; ++q) {
        int n = (int)start + tid + 64*q;
        float pos = (n + 0.5f) * (1.0f/256.0f) - 0.5f;
        pos = fminf(fmaxf(pos, 0.0f), 127.0f);
        int i0 = (int)pos;
        float w = pos - (float)i0;
        int i1 = (i0 + 1 > 127) ? 127 : i0 + 1;
        float x0 = impulse[b*128 + i0]; x0 *= x0;
        float x1 = impulse[b*128 + i1]; x1 *= x1;
        float iv = (x0*(1.0f - w) + x1*w) * noise[b*NSAMP + n];
        op[q] = make_float2(dl[tid + 64*q], iv);
    }
}

// ---------------------------------------------------------------------------
// Kernel 2: forward 512-pt FFT over n1 per (s, n2); input transposed (coalesced),
// three radix-8 Stockham stages through LDS, four-step twiddle w_N^{-n2*k1},
// store G[n2*512 + k1].
__global__ void fft512_fwd_kernel(const float2* __restrict__ src,
                                  float2* __restrict__ dst) {
    const int j  = threadIdx.x;          // 64
    const int s  = blockIdx.x >> 6;
    const int n2 = blockIdx.x & 63;
    __shared__ float2 buf[2][576];
    const float sign = -1.0f;

    const float2* sp = src + s * NSAMP;
    float2 v[8], X[8];
#pragma unroll
    for (int q = 0; q < 8; ++q) v[q] = sp[n2*512 + j + 64*q];

    bfly8(v, sign, X);
#pragma unroll
    for (int r = 0; r < 8; ++r) buf[0][phi(8*j + r)] = X[r];
    __syncthreads();
#pragma unroll
    for (int q = 0; q < 8; ++q) v[q] = buf[0][phi(j + 64*q)];
    int jm = j & 7;
    twiddle_q(v, sign * TWO_PI * (float)jm * (1.0f/64.0f));
    bfly8(v, sign, X);
#pragma unroll
    for (int r = 0; r < 8; ++r) buf[1][phi(((j>>3)<<6) + jm + (r<<3))] = X[r];
    __syncthreads();
#pragma unroll
    for (int q = 0; q < 8; ++q) v[q] = buf[1][phi(j + 64*q)];
    twiddle_q(v, sign * TWO_PI * (float)j * (1.0f/512.0f));
    bfly8(v, sign, X);

    float2* dp = dst + s * NSAMP + n2 * 512;
#pragma unroll
    for (int r = 0; r < 8; ++r) {
        int k1 = j + 64*r;
        int pr = (n2 * k1) & (NSAMP - 1);
        float sa, ca; __sincosf(sign * TWO_PI * (float)pr * (1.0f/32768.0f), &sa, &ca);
        dp[k1] = cmul(X[r], make_float2(ca, sa));
    }
}

// ---------------------------------------------------------------------------
// Kernel 3 (MEGA): per block: 8 spectrum columns = 4 Hermitian pairs.
//   step 1: fwd 64-pt FFT over n2 for each column  -> Z[k1][k2] in LDS
//   step 2: pointwise S = D*I*fv*SCALE in LDS (pair (k, N-k) both in-block;
//           S[N-k] = conj(D*I)*fv*SCALE)
//   step 3: inv 64-pt FFT over k2 per column -> T[k1][n2]; twiddle
//           w_N^{+n2*k1}; store H[n2*512 + k1].
// Columns: group g in [0,64): lows {4g..4g+3}; highs = 512 - low (g=0:
// lows {0..3}, highs {256,511,510,509}; cols 0 and 256 self-paired).
__global__ void mega_kernel(const float2* __restrict__ G,
                            float2* __restrict__ H,
                            const float* __restrict__ filt) {
    const int l  = threadIdx.x;          // 64
    const int cc = l & 7, jj = l >> 3;
    const int s  = blockIdx.x >> 6;
    const int g  = blockIdx.x & 63;
    __shared__ float2 Z[8][65];
    __shared__ float2 buf[576];
    __shared__ float fs[NFR];
    __shared__ int cols[8];

    if (l < NFR) fs[l] = 1.0f/(1.0f + __expf(-filt[s*NFR + l]));
    if (l < 8) {
        int col;
        if (l < 4)        col = 4*g + l;
        else if (g == 0)  col = (l == 4) ? 256 : 512 - (l - 4);
        else              col = 512 - 4*g - (l - 4);
        cols[l] = col;
    }
    __syncthreads();

    const float2* sp = G + s * NSAMP;
    const int mycol = cols[cc];
    float2 v[8], X[8];

    // ---- step 1: forward 64-pt FFT (sign=-1) over n2, column mycol ----
#pragma unroll
    for (int q = 0; q < 8; ++q) v[q] = sp[(jj + 8*q)*512 + mycol];
    bfly8(v, -1.0f, X);
#pragma unroll
    for (int r = 0; r < 8; ++r) buf[phi(cc*64 + jj*8 + r)] = X[r];
    __syncthreads();
#pragma unroll
    for (int q = 0; q < 8; ++q) v[q] = buf[phi(cc*64 + jj + 8*q)];
    twiddle_q(v, -TWO_PI * (float)jj * (1.0f/64.0f));
    bfly8(v, -1.0f, X);
#pragma unroll
    for (int r = 0; r < 8; ++r) Z[cc][jj + 8*r] = X[r];   // k2 = jj+8r
    __syncthreads();

    // ---- step 2: pointwise in LDS ----
    const float SCALE = 1.0f / (32768.0f * 181.01933598375618f); // N^{-3/2}
    // general pairs: (c,k2) <-> (c+4, 63-k2), c in [0,4) (skip c==0 when g==0)
#pragma unroll
    for (int it = 0; it < 4; ++it) {
        int c  = l & 3;
        int k2 = (l >> 2) + 16*it;
        if (!(g == 0 && c == 0)) {
            int col = cols[c];
            float2 Zk = Z[c][k2];
            float2 Zr = Z[c+4][63 - k2];
            float2 Zrc = make_float2(Zr.x, -Zr.y);
            float2 D = make_float2(0.5f*(Zk.x + Zrc.x), 0.5f*(Zk.y + Zrc.y));
            float2 df = make_float2(Zk.x - Zrc.x, Zk.y - Zrc.y);
            float2 I = make_float2(0.5f*df.y, -0.5f*df.x);
            int k = col + 512*k2;
            int jjb = (k <= NSAMP - k) ? k : NSAMP - k;
            float fv = 0.0f;
            if (jjb < NSAMP/2) {
                float pos = (jjb + 0.5f) * (1.0f/1024.0f) - 0.5f;
                pos = fminf(fmaxf(pos, 0.0f), 15.0f);
                int i0 = (int)pos;
                float w = pos - (float)i0;
                int i1 = (i0 + 1 > 15) ? 15 : i0 + 1;
                fv = fs[i0]*(1.0f - w) + fs[i1]*w;
            }
            float2 spec = cmul(D, I);
            float gs = fv * SCALE;
            Z[c][k2]        = make_float2( spec.x*gs,  spec.y*gs);
            Z[c+4][63 - k2] = make_float2( spec.x*gs, -spec.y*gs);
        }
    }
    // special self-paired columns for g==0: col 0 (c=0) and col 256 (c=4)
    if (g == 0) {
        if (l <= 32) {            // col 0: k2 <-> (64-k2)&63, k2 in [0,32]
            int k2 = l, k2p = (64 - k2) & 63;
            float2 Zk = Z[0][k2];
            float2 Zr = Z[0][k2p];
            float2 Zrc = make_float2(Zr.x, -Zr.y);
            float2 D = make_float2(0.5f*(Zk.x + Zrc.x), 0.5f*(Zk.y + Zrc.y));
            float2 df = make_float2(Zk.x - Zrc.x, Zk.y - Zrc.y);
            float2 I = make_float2(0.5f*df.y, -0.5f*df.x);
            int k = 512*k2;
            int jjb = (k <= NSAMP - k) ? k : NSAMP - k;
            float fv = 0.0f;
            if (jjb < NSAMP/2) {
                float pos = (jjb + 0.5f) * (1.0f/1024.0f) - 0.5f;
                pos = fminf(fmaxf(pos, 0.0f), 15.0f);
                int i0 = (int)pos;
                float w = pos - (float)i0;
                int i1 = (i0 + 1 > 15) ? 15 : i0 + 1;
                fv = fs[i0]*(1.0f - w) + fs[i1]*w;
            }
            float2 spec = cmul(D, I);
            float gs = fv * SCALE;
            Z[0][k2]  = make_float2( spec.x*gs,  spec.y*gs);
            Z[0][k2p] = make_float2( spec.x*gs, -spec.y*gs);
        }
        if (l < 32) {             // col 256: k2 <-> 63-k2, k2 in [0,32)
            int k2 = l, k2p = 63 - k2;
            float2 Zk = Z[4][k2];
            float2 Zr = Z[4][k2p];
            float2 Zrc = make_float2(Zr.x, -Zr.y);
            float2 D = make_float2(0.5f*(Zk.x + Zrc.x), 0.5f*(Zk.y + Zrc.y));
            float2 df = make_float2(Zk.x - Zrc.x, Zk.y - Zrc.y);
            float2 I = make_float2(0.5f*df.y, -0.5f*df.x);
            int k = 256 + 512*k2;
            int jjb = (k <= NSAMP - k) ? k : NSAMP - k;
            float fv = 0.0f;
            {
                float pos = (jjb + 0.5f) * (1.0f/1024.0f) - 0.5f;
                pos = fminf(fmaxf(pos, 0.0f), 15.0f);
                int i0 = (int)pos;
                float w = pos - (float)i0;
                int i1 = (i0 + 1 > 15) ? 15 : i0 + 1;
                fv = fs[i0]*(1.0f - w) + fs[i1]*w;
            }
            float2 spec = cmul(D, I);
            float gs = fv * SCALE;
            Z[4][k2]  = make_float2( spec.x*gs,  spec.y*gs);
            Z[4][k2p] = make_float2( spec.x*gs, -spec.y*gs);
        }
    }
    __syncthreads();

    // ---- step 3: inverse 64-pt FFT (sign=+1) over k2, column mycol ----
#pragma unroll
    for (int q = 0; q < 8; ++q) v[q] = Z[cc][jj + 8*q];
    bfly8(v, 1.0f, X);
#pragma unroll
    for (int r = 0; r < 8; ++r) buf[phi(cc*64 + jj*8 + r)] = X[r];
    __syncthreads();
#pragma unroll
    for (int q = 0; q < 8; ++q) v[q] = buf[phi(cc*64 + jj + 8*q)];
    twiddle_q(v, TWO_PI * (float)jj * (1.0f/64.0f));
    bfly8(v, 1.0f, X);

    // T[mycol][n2], n2 = jj+8r; twiddle w_N^{+n2*mycol}; store H[n2*512+mycol]
    float2* hp = H + s * NSAMP + mycol;
#pragma unroll
    for (int r = 0; r < 8; ++r) {
        int n2 = jj + 8*r;
        int pr = (n2 * mycol) & (NSAMP - 1);
        float sa, ca; __sincosf(TWO_PI * (float)pr * (1.0f/32768.0f), &sa, &ca);
        hp[n2*512] = cmul(X[r], make_float2(ca, sa));
    }
}

// ---------------------------------------------------------------------------
// Kernel 4: final inverse 512-pt FFT over k1 per (s, n2); input H[n2*512+k1]
// coalesced; NO extra twiddle (already applied in mega); store real part:
// out[s][64*n1 + n2], n1 = j + 64r.
__global__ void fft512_out_kernel(const float2* __restrict__ H,
                                  float* __restrict__ out) {
    const int j  = threadIdx.x;          // 64
    const int s  = blockIdx.x >> 6;
    const int n2 = blockIdx.x & 63;
    __shared__ float2 buf[2][576];
    const float sign = 1.0f;

    const float2* sp = H + s * NSAMP;
    float2 v[8], X[8];
#pragma unroll
    for (int q = 0; q < 8; ++q) v[q] = sp[n2*512 + j + 64*q];

    bfly8(v, sign, X);
#pragma unroll
    for (int r = 0; r < 8; ++r) buf[0][phi(8*j + r)] = X[r];
    __syncthreads();
#pragma unroll
    for (int q = 0; q < 8; ++q) v[q] = buf[0][phi(j + 64*q)];
    int jm = j & 7;
    twiddle_q(v, sign * TWO_PI * (float)jm * (1.0f/64.0f));
    bfly8(v, sign, X);
#pragma unroll
    for (int r = 0; r < 8; ++r) buf[1][phi(((j>>3)<<6) + jm + (r<<3))] = X[r];
    __syncthreads();
#pragma unroll
    for (int q = 0; q < 8; ++q) v[q] = buf[1][phi(j + 64*q)];
    twiddle_q(v, sign * TWO_PI * (float)j * (1.0f/512.0f));
    bfly8(v, sign, X);

    float* op = out + s * NSAMP + n2;
#pragma unroll
    for (int r = 0; r < 8; ++r) op[64*j + 4096*r] = X[r].x;
}

// ---------------------------------------------------------------------------
extern "C" void kernel_launch(void* const* d_in, const int* in_sizes, int n_in,
                              void* d_out, int out_size, void* d_ws, size_t ws_size,
                              hipStream_t stream) {
    const float* impulse = (const float*)d_in[0];   // [8,128]
    const float* dsel    = (const float*)d_in[1];   // [8,512,16]
    const float* damping = (const float*)d_in[2];   // [8,1]
    const float* filt    = (const float*)d_in[3];   // [8,16]
    const float* noise   = (const float*)d_in[4];   // [8,1,32768]
    // d_in[5] (delays, 64 MB): pure structure delays[i,n] = [ (i+1) | n ] — never read.
    float* out = (float*)d_out;                     // [8,32768]

    float2* A = (float2*)d_ws;                      // 2 MB
    float2* B = A + BATCH * NSAMP;                  // 2 MB

    // R13: revert to verified-best r3 structure (135.2 us; r0 134.5).
    // Ledger: 3-node column-fusion +37, persistent+dev-barriers +146,
    // per-batch fat blocks +78, 4-wave wgs +3. Windowed build (required
    // by sieve) forces the strided 512-FFT behind a global transpose ->
    // 4 stream-ordered nodes is structurally minimal on this part.
    build_kernel     <<<dim3(512), dim3(64), 0, stream>>>(impulse, dsel, damping, noise, A);
    fft512_fwd_kernel<<<dim3(512), dim3(64), 0, stream>>>(A, B);
    mega_kernel      <<<dim3(512), dim3(64), 0, stream>>>(B, A, filt);
    fft512_out_kernel<<<dim3(512), dim3(64), 0, stream>>>(A, out);
}